// Round 6
// baseline (285.596 us; speedup 1.0000x reference)
//
#include <hip/hip_runtime.h>

#define IH 256
#define IW 256
#define FH 128
#define FW 128
#define NB 16
#define ICH 33
#define NF 10
#define NC 30            // warped channels = NF*3
#define PL (FH * FW)     // 16384
#define SPLIT 8                              // 16-row parts per (b,c)
#define ROWS_PP (FH / SPLIT)                 // 16
#define LOSS_BLOCKS (NB * NC * SPLIT)        // 3840
#define SMOOTH_BLOCKS 480
#define HALO 5
#define SROWS (ROWS_PP + 2 * HALO + 1)       // 27 rows staged -> 13824 B LDS (8 blocks/CU)
#define PART_STRIDE 8

// fast exact charbonnier: (g^2 + 1e-6)^0.4, arg > 0 so hw log2/exp2 safe (~1ulp)
__device__ __forceinline__ float charb(float g) {
    float t = fmaf(g, g, 1e-6f);
    return __builtin_amdgcn_exp2f(0.4f * __builtin_amdgcn_logf(t));
}

// align-corners bilinear sample of a 256x256 plane at 128-grid point (Y,X).
// Scalar form; hot use is the rare out-of-halo fallback.
__device__ __forceinline__ float resized_at(const float* __restrict__ plane, int Y, int X) {
    const float s = (float)(255.0 / 127.0);
    float fy = (float)Y * s;
    float fx = (float)X * s;
    int y0 = (int)fy; y0 = y0 > IH - 2 ? IH - 2 : y0;
    int x0 = (int)fx; x0 = x0 > IW - 2 ? IW - 2 : x0;
    float wy = fy - (float)y0;
    float wx = fx - (float)x0;
    const float* p0 = plane + y0 * IW + x0;
    float v00 = p0[0], v01 = p0[1];
    float v10 = p0[IW], v11 = p0[IW + 1];
    float r0 = v00 * (1.f - wy) + v10 * wy;   // y-interp first (matches reference)
    float r1 = v01 * (1.f - wy) + v11 * wy;
    return r0 * (1.f - wx) + r1 * wx;
}

// ============ Mega kernel: smooth (blocks [0,480)) + loss (blocks [480,4320)) ========
// Round-1 structure (scalar ref loads, bounds 8 -- spill-free) with:
//  * float4 STAGING (isolated pre-barrier loop; regs die at the barrier; bit-exact
//    since floor(X*255/127)==2X so an output pair reads exactly one aligned float4
//    per source row -- harness-verified rounds 3/4).
//  * flow PREFETCH: iteration k+1's flow float2s issued before computing iteration k,
//    pulling global-load latency off the serial flow->LDS-gather chain.
// WRITE_SIZE is the spill tripwire: r3/r4's float4 MAIN loop spilled (156/34.7 MB);
// this version keeps the main loop scalar so writes must be ~67 KB.
__global__ void __launch_bounds__(256, 8) mega(const float* __restrict__ images,
                                               const float* __restrict__ flows,
                                               float* __restrict__ ws)
{
    float* part_loss   = ws;                                // [3840][8]
    float* part_smooth = ws + LOSS_BLOCKS * PART_STRIDE;    // [480]

    if (blockIdx.x < SMOOTH_BLOCKS) {
        // ---------- smoothness partial: scalar (low register pressure, no spill) ----
        int sb = blockIdx.x;
        const int total = NB * NF * PL;
        float s = 0.f;
        for (int i = sb * 256 + threadIdx.x; i < total; i += SMOOTH_BLOCKS * 256) {
            int w = i & (FW - 1);
            int h = (i >> 7) & (FH - 1);
            int f = (i >> 14) % NF;
            int b = i / (NF * PL);
            int pix = h * FW + w;
            const float* xp = flows + (size_t)(b * 2 * NF + 2 * f) * PL;
            const float* yp = xp + PL;

            float g1x, g1y;   // flow-channel axis (stride 2 planes)
            if (f == 0)           { g1x = xp[2 * PL + pix] - xp[pix];
                                    g1y = yp[2 * PL + pix] - yp[pix]; }
            else if (f == NF - 1) { g1x = xp[pix] - xp[pix - 2 * PL];
                                    g1y = yp[pix] - yp[pix - 2 * PL]; }
            else                  { g1x = 0.5f * (xp[2 * PL + pix] - xp[pix - 2 * PL]);
                                    g1y = 0.5f * (yp[2 * PL + pix] - yp[pix - 2 * PL]); }

            float g2x, g2y;   // H axis
            if (h == 0)           { g2x = xp[pix + FW] - xp[pix];
                                    g2y = yp[pix + FW] - yp[pix]; }
            else if (h == FH - 1) { g2x = xp[pix] - xp[pix - FW];
                                    g2y = yp[pix] - yp[pix - FW]; }
            else                  { g2x = 0.5f * (xp[pix + FW] - xp[pix - FW]);
                                    g2y = 0.5f * (yp[pix + FW] - yp[pix - FW]); }

            s += charb(g1x) + charb(g2x) + charb(g1y) + charb(g2y);
        }
        for (int off = 32; off > 0; off >>= 1) s += __shfl_down(s, off, 64);
        __shared__ float shs[4];
        int wave = threadIdx.x >> 6;
        if ((threadIdx.x & 63) == 0) shs[wave] = s;
        __syncthreads();
        if (threadIdx.x == 0)
            part_smooth[sb] = shs[0] + shs[1] + shs[2] + shs[3];
        return;
    }

    // ---------- loss block: (bc, 16-row part p) ----------
    __shared__ float slds[SROWS * FW];     // resized src part-plane + halo
    int blk = blockIdx.x - SMOOTH_BLOCKS;  // 0..3839
    int bc = blk >> 3;
    int p  = blk & 7;
    int b = bc / NC;
    int c = bc % NC;
    int f = c / 3;
    const float* ref_img  = images + (size_t)(b * ICH + c) * (IH * IW);
    const float* src_img  = images + (size_t)(b * ICH + 3 + c) * (IH * IW);
    const float* fx_plane = flows + (size_t)(b * 2 * NF + 2 * f) * PL;
    const float* fy_plane = fx_plane + PL;

    int lo = p * ROWS_PP - HALO;                    if (lo < 0) lo = 0;
    int hi = p * ROWS_PP + ROWS_PP - 1 + HALO + 1;  if (hi > FH - 1) hi = FH - 1;
    int npair = (hi - lo + 1) * 64;

    const float sR = (float)(255.0 / 127.0);

    // stage: resize src rows [lo,hi] into LDS, one output PAIR per iteration:
    // two aligned float4 loads, fully coalesced across lanes (bit-exact, r3/r4).
    #pragma unroll 2
    for (int j = threadIdx.x; j < npair; j += 256) {
        int row = lo + (j >> 6);
        int xps = j & 63;
        float fy = (float)row * sR;
        int y0 = (int)fy; if (y0 > IH - 2) y0 = IH - 2;
        float wy = fy - (float)y0;
        float4 t = *((const float4*)(src_img + y0 * IW) + xps);
        float4 u = *((const float4*)(src_img + (y0 + 1) * IW) + xps);
        float fx0 = (float)(2 * xps) * sR;
        float fx1 = (float)(2 * xps + 1) * sR;
        int x00 = (int)fx0; if (x00 > IW - 2) x00 = IW - 2;
        int x01 = (int)fx1; if (x01 > IW - 2) x01 = IW - 2;
        float wx0 = fx0 - (float)x00;
        float wx1 = fx1 - (float)x01;
        float ar0 = t.x * (1.f - wy) + u.x * wy;
        float ar1 = t.y * (1.f - wy) + u.y * wy;
        float br0 = t.z * (1.f - wy) + u.z * wy;
        float br1 = t.w * (1.f - wy) + u.w * wy;
        float o0 = ar0 * (1.f - wx0) + ar1 * wx0;
        float o1 = br0 * (1.f - wx1) + br1 * wx1;
        ((float2*)slds)[(row - lo) * 64 + xps] = make_float2(o0, o1);
    }
    __syncthreads();

    // per-thread x-side resize weights are loop-invariant: hoist
    int xp = threadIdx.x & 63;
    int w0 = 2 * xp;                                 // pixels w0, w0+1
    float fx0 = (float)w0 * sR;
    float fx1 = (float)(w0 + 1) * sR;
    int x00 = (int)fx0; if (x00 > IW - 2) x00 = IW - 2;
    int x01 = (int)fx1; if (x01 > IW - 2) x01 = IW - 2;
    float wxr0 = fx0 - (float)x00;
    float wxr1 = fx1 - (float)x01;

    const float2* fx2 = (const float2*)fx_plane;
    const float2* fy2 = (const float2*)fy_plane;

    float s_ref = 0.f, s_w = 0.f, s_r2 = 0.f, s_w2 = 0.f, s_rw = 0.f, s_pix = 0.f;
    int base2 = p * (ROWS_PP * FW / 2);              // float2 pixel-pair index base

    // software pipeline: flows for iteration k+1 issued before computing iteration k
    float2 fl_x = fx2[base2 + threadIdx.x];
    float2 fl_y = fy2[base2 + threadIdx.x];
    #pragma unroll 2
    for (int k = 0; k < ROWS_PP * FW / 2 / 256; k++) {   // 4 iterations
        int p2 = base2 + (int)threadIdx.x + k * 256;
        int pn = p2 + 256; if (pn > PL / 2 - 1) pn = PL / 2 - 1;  // clamped prefetch idx
        float2 cfl_x = fl_x, cfl_y = fl_y;
        fl_x = fx2[pn];
        fl_y = fy2[pn];

        int h = p2 >> 6;
        // --- ref resize, both pixels: 8 scalar loads (round-1 proven, spill-free)
        float fyR = (float)h * sR;
        int yr0 = (int)fyR; if (yr0 > IH - 2) yr0 = IH - 2;
        float wyr = fyR - (float)yr0;
        const float* rp0 = ref_img + yr0 * IW;
        const float* rp1 = rp0 + IW;
        float a00 = rp0[x00], a01 = rp0[x00 + 1], a10 = rp1[x00], a11 = rp1[x00 + 1];
        float b00 = rp0[x01], b01 = rp0[x01 + 1], b10 = rp1[x01], b11 = rp1[x01 + 1];

        float ar0 = a00 * (1.f - wyr) + a10 * wyr;
        float ar1 = a01 * (1.f - wyr) + a11 * wyr;
        float ref0 = ar0 * (1.f - wxr0) + ar1 * wxr0;
        float br0 = b00 * (1.f - wyr) + b10 * wyr;
        float br1 = b01 * (1.f - wyr) + b11 * wyr;
        float ref1 = br0 * (1.f - wxr1) + br1 * wxr1;

        // --- warp sample from LDS, both pixels
        float wv[2];
        #pragma unroll
        for (int q = 0; q < 2; q++) {
            float gx = (float)(w0 + q) + (q ? cfl_x.y : cfl_x.x);
            float gy = (float)h + (q ? cfl_y.y : cfl_y.x);
            float x0f = floorf(gx), y0f = floorf(gy);
            float wx = gx - x0f, wy = gy - y0f;
            int x0 = (int)x0f; x0 = min(max(x0, 0), FW - 1);
            int y0 = (int)y0f; y0 = min(max(y0, 0), FH - 1);
            int x1 = min(x0 + 1, FW - 1);
            int y1 = min(y0 + 1, FH - 1);
            float v00, v01, v10, v11;
            if (y0 >= lo && y1 <= hi) {     // true unless |flow| > 5 sigma
                const float* r0 = slds + ((y0 - lo) << 7);
                const float* r1 = slds + ((y1 - lo) << 7);
                v00 = r0[x0]; v01 = r0[x1];
                v10 = r1[x0]; v11 = r1[x1];
            } else {                         // exact recompute from global (rare)
                v00 = resized_at(src_img, y0, x0);
                v01 = resized_at(src_img, y0, x1);
                v10 = resized_at(src_img, y1, x0);
                v11 = resized_at(src_img, y1, x1);
            }
            float top = v00 * (1.f - wx) + v01 * wx;
            float bot = v10 * (1.f - wx) + v11 * wx;
            wv[q] = top * (1.f - wy) + bot * wy;
        }

        s_ref += ref0 + ref1;
        s_w   += wv[0] + wv[1];
        s_r2  += ref0 * ref0 + ref1 * ref1;
        s_w2  += wv[0] * wv[0] + wv[1] * wv[1];
        s_rw  += ref0 * wv[0] + ref1 * wv[1];
        s_pix += charb(ref0 - wv[0]) + charb(ref1 - wv[1]);
    }
    for (int off = 32; off > 0; off >>= 1) {
        s_ref += __shfl_down(s_ref, off, 64);
        s_w   += __shfl_down(s_w, off, 64);
        s_r2  += __shfl_down(s_r2, off, 64);
        s_w2  += __shfl_down(s_w2, off, 64);
        s_rw  += __shfl_down(s_rw, off, 64);
        s_pix += __shfl_down(s_pix, off, 64);
    }
    __shared__ float sh[4][6];
    int wave = threadIdx.x >> 6;
    if ((threadIdx.x & 63) == 0) {
        sh[wave][0] = s_ref; sh[wave][1] = s_w; sh[wave][2] = s_r2;
        sh[wave][3] = s_w2;  sh[wave][4] = s_rw; sh[wave][5] = s_pix;
    }
    __syncthreads();
    if (threadIdx.x < 6) {
        int j = threadIdx.x;
        part_loss[blk * PART_STRIDE + j] = sh[0][j] + sh[1][j] + sh[2][j] + sh[3][j];
    }
}

// ============ finalize: SSIM per (b,c) + combine to scalar ============
__global__ void __launch_bounds__(512) finalize2(const float* __restrict__ ws,
                                                 float* __restrict__ out)
{
    const float* part_loss   = ws;
    const float* part_smooth = ws + LOSS_BLOCKS * PART_STRIDE;
    int tid = threadIdx.x;
    float ssim = 0.f, pix = 0.f, smo = 0.f;
    if (tid < NB * NC) {
        float t0 = 0, t1 = 0, t2 = 0, t3 = 0, t4 = 0;
        for (int q = 0; q < SPLIT; q++) {
            const float* a = part_loss + (SPLIT * tid + q) * PART_STRIDE;
            t0 += a[0]; t1 += a[1]; t2 += a[2]; t3 += a[3]; t4 += a[4];
            pix += a[5];
        }
        const float N = (float)PL;
        float mu1 = t0 / N, mu2 = t1 / N;
        float var1 = (t2 - t0 * mu1) / (N - 1.f);
        float var2 = (t3 - t1 * mu2) / (N - 1.f);
        float s12 = t4 / N - mu1 * mu2;
        float num = (2.f * mu1 * mu2 + 1e-4f) * (2.f * s12 + 1e-3f);
        float den = (mu1 * mu1 + mu2 * mu2 + 1e-4f) * (var1 + var2 + 1e-3f);
        ssim = num / den;
    }
    if (tid < SMOOTH_BLOCKS) smo = part_smooth[tid];
    __shared__ float sa[512], sb[512], sc[512];
    sa[tid] = ssim; sb[tid] = pix; sc[tid] = smo;
    __syncthreads();
    for (int off = 256; off > 0; off >>= 1) {
        if (tid < off) {
            sa[tid] += sa[tid + off];
            sb[tid] += sb[tid + off];
            sc[tid] += sc[tid + off];
        }
        __syncthreads();
    }
    if (tid == 0) {
        out[0] = sb[0] / (float)(NB * NC * PL)
               + 0.01f * (sc[0] / (float)(NB * NF * PL))
               + sa[0] / (float)(NB * NC);
    }
}

extern "C" void kernel_launch(void* const* d_in, const int* in_sizes, int n_in,
                              void* d_out, int out_size, void* d_ws, size_t ws_size,
                              hipStream_t stream) {
    const float* images = (const float*)d_in[0];
    const float* flows  = (const float*)d_in[1];
    float* ws = (float*)d_ws;   // ~125 KB of plain-stored partials
    mega<<<SMOOTH_BLOCKS + LOSS_BLOCKS, 256, 0, stream>>>(images, flows, ws);
    finalize2<<<1, 512, 0, stream>>>(ws, (float*)d_out);
}

// Round 7
// 223.421 us; speedup vs baseline: 1.2783x; 1.2783x over previous
//
#include <hip/hip_runtime.h>

#define IH 256
#define IW 256
#define FH 128
#define FW 128
#define NB 16
#define ICH 33
#define NF 10
#define NC 30            // warped channels = NF*3
#define PL (FH * FW)     // 16384
#define SPLIT 8                              // 16-row parts per (b,c) -> small LDS, 8 blocks/CU
#define ROWS_PP (FH / SPLIT)                 // 16
#define LOSS_BLOCKS (NB * NC * SPLIT)        // 3840
#define SMOOTH_BLOCKS 480
#define HALO 5
#define SROWS (ROWS_PP + 2 * HALO + 1)       // 27 rows staged -> 13824 B LDS (8 blocks/CU)
#define PART_STRIDE 8

// fast exact charbonnier: (g^2 + 1e-6)^0.4, arg > 0 so hw log2/exp2 safe (~1ulp)
__device__ __forceinline__ float charb(float g) {
    float t = fmaf(g, g, 1e-6f);
    return __builtin_amdgcn_exp2f(0.4f * __builtin_amdgcn_logf(t));
}

// align-corners bilinear sample of a 256x256 plane at 128-grid point (Y,X).
// Bit-exact vs jax reference (absmax 0.0 across all rounds).
// NOTE (r3/r4/r6 lesson): do NOT replace the scalar loads here or in the staging /
// ref paths with float4 variants — every such change tripped the register allocator
// into scratch spill (WRITE_SIZE 67.5 KB -> 35..186 MB) and regressed 15-60 us.
__device__ __forceinline__ float resized_at(const float* __restrict__ plane, int Y, int X) {
    const float s = (float)(255.0 / 127.0);
    float fy = (float)Y * s;
    float fx = (float)X * s;
    int y0 = (int)fy; y0 = y0 > IH - 2 ? IH - 2 : y0;
    int x0 = (int)fx; x0 = x0 > IW - 2 ? IW - 2 : x0;
    float wy = fy - (float)y0;
    float wx = fx - (float)x0;
    const float* p0 = plane + y0 * IW + x0;
    float v00 = p0[0], v01 = p0[1];
    float v10 = p0[IW], v11 = p0[IW + 1];
    float r0 = v00 * (1.f - wy) + v10 * wy;   // y-interp first (matches reference)
    float r1 = v01 * (1.f - wy) + v11 * wy;
    return r0 * (1.f - wx) + r1 * wx;
}

// ============ Mega kernel: smooth (blocks [0,480)) + loss (blocks [480,4320)) ========
// No atomics, no zero-init: every block plain-stores its partial; finalize (separate
// dispatch = device-wide coherence point) combines.
__global__ void __launch_bounds__(256, 8) mega(const float* __restrict__ images,
                                               const float* __restrict__ flows,
                                               float* __restrict__ ws)
{
    float* part_loss   = ws;                                // [3840][8]
    float* part_smooth = ws + LOSS_BLOCKS * PART_STRIDE;    // [480]

    if (blockIdx.x < SMOOTH_BLOCKS) {
        // ---------- smoothness partial: gradient along flow-index axis and H axis ----
        int sb = blockIdx.x;
        const int total = NB * NF * PL;
        float s = 0.f;
        for (int i = sb * 256 + threadIdx.x; i < total; i += SMOOTH_BLOCKS * 256) {
            int w = i & (FW - 1);
            int h = (i >> 7) & (FH - 1);
            int f = (i >> 14) % NF;
            int b = i / (NF * PL);
            int pix = h * FW + w;
            const float* xp = flows + (size_t)(b * 2 * NF + 2 * f) * PL;
            const float* yp = xp + PL;

            float g1x, g1y;   // flow-channel axis (stride 2 planes)
            if (f == 0)           { g1x = xp[2 * PL + pix] - xp[pix];
                                    g1y = yp[2 * PL + pix] - yp[pix]; }
            else if (f == NF - 1) { g1x = xp[pix] - xp[pix - 2 * PL];
                                    g1y = yp[pix] - yp[pix - 2 * PL]; }
            else                  { g1x = 0.5f * (xp[2 * PL + pix] - xp[pix - 2 * PL]);
                                    g1y = 0.5f * (yp[2 * PL + pix] - yp[pix - 2 * PL]); }

            float g2x, g2y;   // H axis
            if (h == 0)           { g2x = xp[pix + FW] - xp[pix];
                                    g2y = yp[pix + FW] - yp[pix]; }
            else if (h == FH - 1) { g2x = xp[pix] - xp[pix - FW];
                                    g2y = yp[pix] - yp[pix - FW]; }
            else                  { g2x = 0.5f * (xp[pix + FW] - xp[pix - FW]);
                                    g2y = 0.5f * (yp[pix + FW] - yp[pix - FW]); }

            s += charb(g1x) + charb(g2x) + charb(g1y) + charb(g2y);
        }
        for (int off = 32; off > 0; off >>= 1) s += __shfl_down(s, off, 64);
        __shared__ float shs[4];
        int wave = threadIdx.x >> 6;
        if ((threadIdx.x & 63) == 0) shs[wave] = s;
        __syncthreads();
        if (threadIdx.x == 0)
            part_smooth[sb] = shs[0] + shs[1] + shs[2] + shs[3];
        return;
    }

    // ---------- loss block: (bc, 16-row part p) ----------
    __shared__ float slds[SROWS * FW];     // resized src part-plane + halo
    int blk = blockIdx.x - SMOOTH_BLOCKS;  // 0..3839
    int bc = blk >> 3;
    int p  = blk & 7;
    int b = bc / NC;
    int c = bc % NC;
    int f = c / 3;
    const float* ref_img  = images + (size_t)(b * ICH + c) * (IH * IW);
    const float* src_img  = images + (size_t)(b * ICH + 3 + c) * (IH * IW);
    const float* fx_plane = flows + (size_t)(b * 2 * NF + 2 * f) * PL;
    const float* fy_plane = fx_plane + PL;

    int lo = p * ROWS_PP - HALO;                    if (lo < 0) lo = 0;
    int hi = p * ROWS_PP + ROWS_PP - 1 + HALO + 1;  if (hi > FH - 1) hi = FH - 1;
    int nstage = (hi - lo + 1) * FW;

    // stage: resize src rows [lo,hi] into LDS (iterations independent -> ILP)
    #pragma unroll 2
    for (int i = threadIdx.x; i < nstage; i += 256) {
        int y = lo + (i >> 7);
        int x = i & (FW - 1);
        slds[i] = resized_at(src_img, y, x);
    }
    __syncthreads();

    // per-thread w-pair is loop-invariant: hoist all x-side resize weights
    const float sR = (float)(255.0 / 127.0);
    int w0 = (2 * threadIdx.x) & (FW - 1);          // pixels w0, w0+1
    float fx0 = (float)w0 * sR;
    float fx1 = (float)(w0 + 1) * sR;
    int x00 = (int)fx0; if (x00 > IW - 2) x00 = IW - 2;
    int x01 = (int)fx1; if (x01 > IW - 2) x01 = IW - 2;
    float wxr0 = fx0 - (float)x00;
    float wxr1 = fx1 - (float)x01;

    float s_ref = 0.f, s_w = 0.f, s_r2 = 0.f, s_w2 = 0.f, s_rw = 0.f, s_pix = 0.f;
    int base2 = p * (ROWS_PP * FW / 2);              // float2 pixel-pair index base
    for (int i = threadIdx.x; i < ROWS_PP * FW / 2; i += 256) {
        int p2 = base2 + i;
        int px = 2 * p2;
        int h = px >> 7;
        // --- ref resize, both pixels: 8 independent global loads, hoisted x-weights
        float fyR = (float)h * sR;
        int yr0 = (int)fyR; if (yr0 > IH - 2) yr0 = IH - 2;
        float wyr = fyR - (float)yr0;
        const float* rp0 = ref_img + yr0 * IW;
        const float* rp1 = rp0 + IW;
        float a00 = rp0[x00], a01 = rp0[x00 + 1], a10 = rp1[x00], a11 = rp1[x00 + 1];
        float b00 = rp0[x01], b01 = rp0[x01 + 1], b10 = rp1[x01], b11 = rp1[x01 + 1];
        float2 fl_x = ((const float2*)fx_plane)[p2];
        float2 fl_y = ((const float2*)fy_plane)[p2];

        float ar0 = a00 * (1.f - wyr) + a10 * wyr;
        float ar1 = a01 * (1.f - wyr) + a11 * wyr;
        float ref0 = ar0 * (1.f - wxr0) + ar1 * wxr0;
        float br0 = b00 * (1.f - wyr) + b10 * wyr;
        float br1 = b01 * (1.f - wyr) + b11 * wyr;
        float ref1 = br0 * (1.f - wxr1) + br1 * wxr1;

        // --- warp sample from LDS, both pixels
        float wv[2];
        #pragma unroll
        for (int q = 0; q < 2; q++) {
            float gx = (float)(w0 + q) + (q ? fl_x.y : fl_x.x);
            float gy = (float)h + (q ? fl_y.y : fl_y.x);
            float x0f = floorf(gx), y0f = floorf(gy);
            float wx = gx - x0f, wy = gy - y0f;
            int x0 = (int)x0f; x0 = min(max(x0, 0), FW - 1);
            int y0 = (int)y0f; y0 = min(max(y0, 0), FH - 1);
            int x1 = min(x0 + 1, FW - 1);
            int y1 = min(y0 + 1, FH - 1);
            float v00, v01, v10, v11;
            if (y0 >= lo && y1 <= hi) {     // true unless |flow| > 5 sigma
                const float* r0 = slds + ((y0 - lo) << 7);
                const float* r1 = slds + ((y1 - lo) << 7);
                v00 = r0[x0]; v01 = r0[x1];
                v10 = r1[x0]; v11 = r1[x1];
            } else {                         // exact recompute from global (rare)
                v00 = resized_at(src_img, y0, x0);
                v01 = resized_at(src_img, y0, x1);
                v10 = resized_at(src_img, y1, x0);
                v11 = resized_at(src_img, y1, x1);
            }
            float top = v00 * (1.f - wx) + v01 * wx;
            float bot = v10 * (1.f - wx) + v11 * wx;
            wv[q] = top * (1.f - wy) + bot * wy;
        }

        s_ref += ref0 + ref1;
        s_w   += wv[0] + wv[1];
        s_r2  += ref0 * ref0 + ref1 * ref1;
        s_w2  += wv[0] * wv[0] + wv[1] * wv[1];
        s_rw  += ref0 * wv[0] + ref1 * wv[1];
        s_pix += charb(ref0 - wv[0]) + charb(ref1 - wv[1]);
    }
    for (int off = 32; off > 0; off >>= 1) {
        s_ref += __shfl_down(s_ref, off, 64);
        s_w   += __shfl_down(s_w, off, 64);
        s_r2  += __shfl_down(s_r2, off, 64);
        s_w2  += __shfl_down(s_w2, off, 64);
        s_rw  += __shfl_down(s_rw, off, 64);
        s_pix += __shfl_down(s_pix, off, 64);
    }
    __shared__ float sh[4][6];
    int wave = threadIdx.x >> 6;
    if ((threadIdx.x & 63) == 0) {
        sh[wave][0] = s_ref; sh[wave][1] = s_w; sh[wave][2] = s_r2;
        sh[wave][3] = s_w2;  sh[wave][4] = s_rw; sh[wave][5] = s_pix;
    }
    __syncthreads();
    if (threadIdx.x < 6) {
        int k = threadIdx.x;
        part_loss[blk * PART_STRIDE + k] = sh[0][k] + sh[1][k] + sh[2][k] + sh[3][k];
    }
}

// ============ finalize: SSIM per (b,c) + combine to scalar ============
__global__ void __launch_bounds__(512) finalize2(const float* __restrict__ ws,
                                                 float* __restrict__ out)
{
    const float* part_loss   = ws;
    const float* part_smooth = ws + LOSS_BLOCKS * PART_STRIDE;
    int tid = threadIdx.x;
    float ssim = 0.f, pix = 0.f, smo = 0.f;
    if (tid < NB * NC) {
        float t0 = 0, t1 = 0, t2 = 0, t3 = 0, t4 = 0;
        for (int q = 0; q < SPLIT; q++) {
            const float* a = part_loss + (SPLIT * tid + q) * PART_STRIDE;
            t0 += a[0]; t1 += a[1]; t2 += a[2]; t3 += a[3]; t4 += a[4];
            pix += a[5];
        }
        const float N = (float)PL;
        float mu1 = t0 / N, mu2 = t1 / N;
        float var1 = (t2 - t0 * mu1) / (N - 1.f);
        float var2 = (t3 - t1 * mu2) / (N - 1.f);
        float s12 = t4 / N - mu1 * mu2;
        float num = (2.f * mu1 * mu2 + 1e-4f) * (2.f * s12 + 1e-3f);
        float den = (mu1 * mu1 + mu2 * mu2 + 1e-4f) * (var1 + var2 + 1e-3f);
        ssim = num / den;
    }
    if (tid < SMOOTH_BLOCKS) smo = part_smooth[tid];
    __shared__ float sa[512], sb[512], sc[512];
    sa[tid] = ssim; sb[tid] = pix; sc[tid] = smo;
    __syncthreads();
    for (int off = 256; off > 0; off >>= 1) {
        if (tid < off) {
            sa[tid] += sa[tid + off];
            sb[tid] += sb[tid + off];
            sc[tid] += sc[tid + off];
        }
        __syncthreads();
    }
    if (tid == 0) {
        out[0] = sb[0] / (float)(NB * NC * PL)
               + 0.01f * (sc[0] / (float)(NB * NF * PL))
               + sa[0] / (float)(NB * NC);
    }
}

extern "C" void kernel_launch(void* const* d_in, const int* in_sizes, int n_in,
                              void* d_out, int out_size, void* d_ws, size_t ws_size,
                              hipStream_t stream) {
    const float* images = (const float*)d_in[0];
    const float* flows  = (const float*)d_in[1];
    float* ws = (float*)d_ws;   // ~125 KB of plain-stored partials
    mega<<<SMOOTH_BLOCKS + LOSS_BLOCKS, 256, 0, stream>>>(images, flows, ws);
    finalize2<<<1, 512, 0, stream>>>(ws, (float*)d_out);
}

// Round 8
// 223.391 us; speedup vs baseline: 1.2785x; 1.0001x over previous
//
#include <hip/hip_runtime.h>

#define IH 256
#define IW 256
#define FH 128
#define FW 128
#define NB 16
#define ICH 33
#define NF 10
#define NC 30            // warped channels = NF*3
#define PL (FH * FW)     // 16384
#define SPLIT 8                              // 16-row parts per (b,c) -> small LDS, 8 blocks/CU
#define ROWS_PP (FH / SPLIT)                 // 16
#define LOSS_BLOCKS (NB * NC * SPLIT)        // 3840
#define SMOOTH_BLOCKS 480
#define HALO 5
#define SROWS (ROWS_PP + 2 * HALO + 1)       // 27 rows staged -> 13824 B LDS (8 blocks/CU)
#define PART_STRIDE 8

// fast exact charbonnier: (g^2 + 1e-6)^0.4, arg > 0 so hw log2/exp2 safe (~1ulp)
__device__ __forceinline__ float charb(float g) {
    float t = fmaf(g, g, 1e-6f);
    return __builtin_amdgcn_exp2f(0.4f * __builtin_amdgcn_logf(t));
}

// align-corners bilinear sample of a 256x256 plane at 128-grid point (Y,X).
// Bit-exact vs jax reference (absmax 0.0 across all rounds).
// NOTE (r3/r4/r6 lesson): the float4 STAGING variants tripped the register allocator
// into scratch spill (WRITE_SIZE 67.5 KB -> 35..186 MB). Staging stays scalar.
__device__ __forceinline__ float resized_at(const float* __restrict__ plane, int Y, int X) {
    const float s = (float)(255.0 / 127.0);
    float fy = (float)Y * s;
    float fx = (float)X * s;
    int y0 = (int)fy; y0 = y0 > IH - 2 ? IH - 2 : y0;
    int x0 = (int)fx; x0 = x0 > IW - 2 ? IW - 2 : x0;
    float wy = fy - (float)y0;
    float wx = fx - (float)x0;
    const float* p0 = plane + y0 * IW + x0;
    float v00 = p0[0], v01 = p0[1];
    float v10 = p0[IW], v11 = p0[IW + 1];
    float r0 = v00 * (1.f - wy) + v10 * wy;   // y-interp first (matches reference)
    float r1 = v01 * (1.f - wy) + v11 * wy;
    return r0 * (1.f - wx) + r1 * wx;
}

// ============ Mega kernel: smooth (blocks [0,480)) + loss (blocks [480,4320)) ========
// No atomics, no zero-init: every block plain-stores its partial; finalize (separate
// dispatch = device-wide coherence point) combines.
// r8 delta (single change): main-loop ref loads 8 scalars -> 4 float2s. Provably
// aligned: x00 = 4*xp exactly (frac 2xp/127 < 1), x01 = 4xp+2 or the 254 clamp --
// both even -> 8B-aligned pairs. Same loaded values, same FLOP order (bit-exact).
// Targets VMEM instruction issue (10 -> 6 VMEM per pixel-pair), which the r7
// arithmetic puts at ~64 us/CU -- the mega timescale.
__global__ void __launch_bounds__(256, 8) mega(const float* __restrict__ images,
                                               const float* __restrict__ flows,
                                               float* __restrict__ ws)
{
    float* part_loss   = ws;                                // [3840][8]
    float* part_smooth = ws + LOSS_BLOCKS * PART_STRIDE;    // [480]

    if (blockIdx.x < SMOOTH_BLOCKS) {
        // ---------- smoothness partial: gradient along flow-index axis and H axis ----
        int sb = blockIdx.x;
        const int total = NB * NF * PL;
        float s = 0.f;
        for (int i = sb * 256 + threadIdx.x; i < total; i += SMOOTH_BLOCKS * 256) {
            int w = i & (FW - 1);
            int h = (i >> 7) & (FH - 1);
            int f = (i >> 14) % NF;
            int b = i / (NF * PL);
            int pix = h * FW + w;
            const float* xp = flows + (size_t)(b * 2 * NF + 2 * f) * PL;
            const float* yp = xp + PL;

            float g1x, g1y;   // flow-channel axis (stride 2 planes)
            if (f == 0)           { g1x = xp[2 * PL + pix] - xp[pix];
                                    g1y = yp[2 * PL + pix] - yp[pix]; }
            else if (f == NF - 1) { g1x = xp[pix] - xp[pix - 2 * PL];
                                    g1y = yp[pix] - yp[pix - 2 * PL]; }
            else                  { g1x = 0.5f * (xp[2 * PL + pix] - xp[pix - 2 * PL]);
                                    g1y = 0.5f * (yp[2 * PL + pix] - yp[pix - 2 * PL]); }

            float g2x, g2y;   // H axis
            if (h == 0)           { g2x = xp[pix + FW] - xp[pix];
                                    g2y = yp[pix + FW] - yp[pix]; }
            else if (h == FH - 1) { g2x = xp[pix] - xp[pix - FW];
                                    g2y = yp[pix] - yp[pix - FW]; }
            else                  { g2x = 0.5f * (xp[pix + FW] - xp[pix - FW]);
                                    g2y = 0.5f * (yp[pix + FW] - yp[pix - FW]); }

            s += charb(g1x) + charb(g2x) + charb(g1y) + charb(g2y);
        }
        for (int off = 32; off > 0; off >>= 1) s += __shfl_down(s, off, 64);
        __shared__ float shs[4];
        int wave = threadIdx.x >> 6;
        if ((threadIdx.x & 63) == 0) shs[wave] = s;
        __syncthreads();
        if (threadIdx.x == 0)
            part_smooth[sb] = shs[0] + shs[1] + shs[2] + shs[3];
        return;
    }

    // ---------- loss block: (bc, 16-row part p) ----------
    __shared__ float slds[SROWS * FW];     // resized src part-plane + halo
    int blk = blockIdx.x - SMOOTH_BLOCKS;  // 0..3839
    int bc = blk >> 3;
    int p  = blk & 7;
    int b = bc / NC;
    int c = bc % NC;
    int f = c / 3;
    const float* ref_img  = images + (size_t)(b * ICH + c) * (IH * IW);
    const float* src_img  = images + (size_t)(b * ICH + 3 + c) * (IH * IW);
    const float* fx_plane = flows + (size_t)(b * 2 * NF + 2 * f) * PL;
    const float* fy_plane = fx_plane + PL;

    int lo = p * ROWS_PP - HALO;                    if (lo < 0) lo = 0;
    int hi = p * ROWS_PP + ROWS_PP - 1 + HALO + 1;  if (hi > FH - 1) hi = FH - 1;
    int nstage = (hi - lo + 1) * FW;

    // stage: resize src rows [lo,hi] into LDS (iterations independent -> ILP)
    #pragma unroll 2
    for (int i = threadIdx.x; i < nstage; i += 256) {
        int y = lo + (i >> 7);
        int x = i & (FW - 1);
        slds[i] = resized_at(src_img, y, x);
    }
    __syncthreads();

    // per-thread w-pair is loop-invariant: hoist all x-side resize weights
    const float sR = (float)(255.0 / 127.0);
    int w0 = (2 * threadIdx.x) & (FW - 1);          // pixels w0, w0+1
    float fx0 = (float)w0 * sR;
    float fx1 = (float)(w0 + 1) * sR;
    int x00 = (int)fx0; if (x00 > IW - 2) x00 = IW - 2;
    int x01 = (int)fx1; if (x01 > IW - 2) x01 = IW - 2;
    float wxr0 = fx0 - (float)x00;
    float wxr1 = fx1 - (float)x01;

    float s_ref = 0.f, s_w = 0.f, s_r2 = 0.f, s_w2 = 0.f, s_rw = 0.f, s_pix = 0.f;
    int base2 = p * (ROWS_PP * FW / 2);              // float2 pixel-pair index base
    for (int i = threadIdx.x; i < ROWS_PP * FW / 2; i += 256) {
        int p2 = base2 + i;
        int px = 2 * p2;
        int h = px >> 7;
        // --- ref resize, both pixels: 4 float2 loads (8B-aligned by construction)
        float fyR = (float)h * sR;
        int yr0 = (int)fyR; if (yr0 > IH - 2) yr0 = IH - 2;
        float wyr = fyR - (float)yr0;
        const float* rp0 = ref_img + yr0 * IW;
        const float* rp1 = rp0 + IW;
        float2 a0 = *(const float2*)(rp0 + x00);   // a00, a01
        float2 a1 = *(const float2*)(rp1 + x00);   // a10, a11
        float2 b0 = *(const float2*)(rp0 + x01);   // b00, b01
        float2 b1 = *(const float2*)(rp1 + x01);   // b10, b11
        float2 fl_x = ((const float2*)fx_plane)[p2];
        float2 fl_y = ((const float2*)fy_plane)[p2];

        float ar0 = a0.x * (1.f - wyr) + a1.x * wyr;
        float ar1 = a0.y * (1.f - wyr) + a1.y * wyr;
        float ref0 = ar0 * (1.f - wxr0) + ar1 * wxr0;
        float br0 = b0.x * (1.f - wyr) + b1.x * wyr;
        float br1 = b0.y * (1.f - wyr) + b1.y * wyr;
        float ref1 = br0 * (1.f - wxr1) + br1 * wxr1;

        // --- warp sample from LDS, both pixels
        float wv[2];
        #pragma unroll
        for (int q = 0; q < 2; q++) {
            float gx = (float)(w0 + q) + (q ? fl_x.y : fl_x.x);
            float gy = (float)h + (q ? fl_y.y : fl_y.x);
            float x0f = floorf(gx), y0f = floorf(gy);
            float wx = gx - x0f, wy = gy - y0f;
            int x0 = (int)x0f; x0 = min(max(x0, 0), FW - 1);
            int y0 = (int)y0f; y0 = min(max(y0, 0), FH - 1);
            int x1 = min(x0 + 1, FW - 1);
            int y1 = min(y0 + 1, FH - 1);
            float v00, v01, v10, v11;
            if (y0 >= lo && y1 <= hi) {     // true unless |flow| > 5 sigma
                const float* r0 = slds + ((y0 - lo) << 7);
                const float* r1 = slds + ((y1 - lo) << 7);
                v00 = r0[x0]; v01 = r0[x1];
                v10 = r1[x0]; v11 = r1[x1];
            } else {                         // exact recompute from global (rare)
                v00 = resized_at(src_img, y0, x0);
                v01 = resized_at(src_img, y0, x1);
                v10 = resized_at(src_img, y1, x0);
                v11 = resized_at(src_img, y1, x1);
            }
            float top = v00 * (1.f - wx) + v01 * wx;
            float bot = v10 * (1.f - wx) + v11 * wx;
            wv[q] = top * (1.f - wy) + bot * wy;
        }

        s_ref += ref0 + ref1;
        s_w   += wv[0] + wv[1];
        s_r2  += ref0 * ref0 + ref1 * ref1;
        s_w2  += wv[0] * wv[0] + wv[1] * wv[1];
        s_rw  += ref0 * wv[0] + ref1 * wv[1];
        s_pix += charb(ref0 - wv[0]) + charb(ref1 - wv[1]);
    }
    for (int off = 32; off > 0; off >>= 1) {
        s_ref += __shfl_down(s_ref, off, 64);
        s_w   += __shfl_down(s_w, off, 64);
        s_r2  += __shfl_down(s_r2, off, 64);
        s_w2  += __shfl_down(s_w2, off, 64);
        s_rw  += __shfl_down(s_rw, off, 64);
        s_pix += __shfl_down(s_pix, off, 64);
    }
    __shared__ float sh[4][6];
    int wave = threadIdx.x >> 6;
    if ((threadIdx.x & 63) == 0) {
        sh[wave][0] = s_ref; sh[wave][1] = s_w; sh[wave][2] = s_r2;
        sh[wave][3] = s_w2;  sh[wave][4] = s_rw; sh[wave][5] = s_pix;
    }
    __syncthreads();
    if (threadIdx.x < 6) {
        int k = threadIdx.x;
        part_loss[blk * PART_STRIDE + k] = sh[0][k] + sh[1][k] + sh[2][k] + sh[3][k];
    }
}

// ============ finalize: SSIM per (b,c) + combine to scalar ============
__global__ void __launch_bounds__(512) finalize2(const float* __restrict__ ws,
                                                 float* __restrict__ out)
{
    const float* part_loss   = ws;
    const float* part_smooth = ws + LOSS_BLOCKS * PART_STRIDE;
    int tid = threadIdx.x;
    float ssim = 0.f, pix = 0.f, smo = 0.f;
    if (tid < NB * NC) {
        float t0 = 0, t1 = 0, t2 = 0, t3 = 0, t4 = 0;
        for (int q = 0; q < SPLIT; q++) {
            const float* a = part_loss + (SPLIT * tid + q) * PART_STRIDE;
            t0 += a[0]; t1 += a[1]; t2 += a[2]; t3 += a[3]; t4 += a[4];
            pix += a[5];
        }
        const float N = (float)PL;
        float mu1 = t0 / N, mu2 = t1 / N;
        float var1 = (t2 - t0 * mu1) / (N - 1.f);
        float var2 = (t3 - t1 * mu2) / (N - 1.f);
        float s12 = t4 / N - mu1 * mu2;
        float num = (2.f * mu1 * mu2 + 1e-4f) * (2.f * s12 + 1e-3f);
        float den = (mu1 * mu1 + mu2 * mu2 + 1e-4f) * (var1 + var2 + 1e-3f);
        ssim = num / den;
    }
    if (tid < SMOOTH_BLOCKS) smo = part_smooth[tid];
    __shared__ float sa[512], sb[512], sc[512];
    sa[tid] = ssim; sb[tid] = pix; sc[tid] = smo;
    __syncthreads();
    for (int off = 256; off > 0; off >>= 1) {
        if (tid < off) {
            sa[tid] += sa[tid + off];
            sb[tid] += sb[tid + off];
            sc[tid] += sc[tid + off];
        }
        __syncthreads();
    }
    if (tid == 0) {
        out[0] = sb[0] / (float)(NB * NC * PL)
               + 0.01f * (sc[0] / (float)(NB * NF * PL))
               + sa[0] / (float)(NB * NC);
    }
}

extern "C" void kernel_launch(void* const* d_in, const int* in_sizes, int n_in,
                              void* d_out, int out_size, void* d_ws, size_t ws_size,
                              hipStream_t stream) {
    const float* images = (const float*)d_in[0];
    const float* flows  = (const float*)d_in[1];
    float* ws = (float*)d_ws;   // ~125 KB of plain-stored partials
    mega<<<SMOOTH_BLOCKS + LOSS_BLOCKS, 256, 0, stream>>>(images, flows, ws);
    finalize2<<<1, 512, 0, stream>>>(ws, (float*)d_out);
}

// Round 9
// 222.929 us; speedup vs baseline: 1.2811x; 1.0021x over previous
//
#include <hip/hip_runtime.h>

#define IH 256
#define IW 256
#define FH 128
#define FW 128
#define NB 16
#define ICH 33
#define NF 10
#define NC 30            // warped channels = NF*3
#define PL (FH * FW)     // 16384
#define SPLIT 4                              // 32-row parts per (b,c)
#define ROWS_PP (FH / SPLIT)                 // 32
#define LOSS_BLOCKS (NB * NC * SPLIT)        // 1920
#define SMOOTH_BLOCKS 480
#define HALO 3                               // fallback is bit-exact; halo only affects speed
#define SROWS (ROWS_PP + 2 * HALO + 1)       // 39 rows staged -> 19968 B LDS (8 blocks/CU)
#define PART_STRIDE 8

// fast exact charbonnier: (g^2 + 1e-6)^0.4, arg > 0 so hw log2/exp2 safe (~1ulp)
__device__ __forceinline__ float charb(float g) {
    float t = fmaf(g, g, 1e-6f);
    return __builtin_amdgcn_exp2f(0.4f * __builtin_amdgcn_logf(t));
}

// align-corners bilinear sample of a 256x256 plane at 128-grid point (Y,X).
// Bit-exact vs jax reference (absmax 0.0 across all rounds).
// NOTE (r3/r4/r6 lesson): float4 STAGING variants tripped the register allocator
// into scratch spill (WRITE_SIZE 67.5 KB -> 35..186 MB). Staging stays scalar.
__device__ __forceinline__ float resized_at(const float* __restrict__ plane, int Y, int X) {
    const float s = (float)(255.0 / 127.0);
    float fy = (float)Y * s;
    float fx = (float)X * s;
    int y0 = (int)fy; y0 = y0 > IH - 2 ? IH - 2 : y0;
    int x0 = (int)fx; x0 = x0 > IW - 2 ? IW - 2 : x0;
    float wy = fy - (float)y0;
    float wx = fx - (float)x0;
    const float* p0 = plane + y0 * IW + x0;
    float v00 = p0[0], v01 = p0[1];
    float v10 = p0[IW], v11 = p0[IW + 1];
    float r0 = v00 * (1.f - wy) + v10 * wy;   // y-interp first (matches reference)
    float r1 = v01 * (1.f - wy) + v11 * wy;
    return r0 * (1.f - wx) + r1 * wx;
}

// ============ Mega kernel: smooth (blocks [0,480)) + loss (blocks [480,2400)) ========
// r9 delta (constants only vs r8's verified source): SPLIT 8->4, HALO 5->3.
// Mechanism: staging redundancy 27/16=1.69 -> 39/32=1.22 (-28% staging work),
// main loop 4 -> 8 iterations/thread (amortizes barrier + hoisted invariants),
// LDS 19968 B x 8 = 159.7 KB/CU keeps 8 blocks/CU. Pair->thread mapping and
// summation order identical to round 0's SPLIT=4 (absmax 0.0 verified).
__global__ void __launch_bounds__(256, 8) mega(const float* __restrict__ images,
                                               const float* __restrict__ flows,
                                               float* __restrict__ ws)
{
    float* part_loss   = ws;                                // [1920][8]
    float* part_smooth = ws + LOSS_BLOCKS * PART_STRIDE;    // [480]

    if (blockIdx.x < SMOOTH_BLOCKS) {
        // ---------- smoothness partial: gradient along flow-index axis and H axis ----
        int sb = blockIdx.x;
        const int total = NB * NF * PL;
        float s = 0.f;
        for (int i = sb * 256 + threadIdx.x; i < total; i += SMOOTH_BLOCKS * 256) {
            int w = i & (FW - 1);
            int h = (i >> 7) & (FH - 1);
            int f = (i >> 14) % NF;
            int b = i / (NF * PL);
            int pix = h * FW + w;
            const float* xp = flows + (size_t)(b * 2 * NF + 2 * f) * PL;
            const float* yp = xp + PL;

            float g1x, g1y;   // flow-channel axis (stride 2 planes)
            if (f == 0)           { g1x = xp[2 * PL + pix] - xp[pix];
                                    g1y = yp[2 * PL + pix] - yp[pix]; }
            else if (f == NF - 1) { g1x = xp[pix] - xp[pix - 2 * PL];
                                    g1y = yp[pix] - yp[pix - 2 * PL]; }
            else                  { g1x = 0.5f * (xp[2 * PL + pix] - xp[pix - 2 * PL]);
                                    g1y = 0.5f * (yp[2 * PL + pix] - yp[pix - 2 * PL]); }

            float g2x, g2y;   // H axis
            if (h == 0)           { g2x = xp[pix + FW] - xp[pix];
                                    g2y = yp[pix + FW] - yp[pix]; }
            else if (h == FH - 1) { g2x = xp[pix] - xp[pix - FW];
                                    g2y = yp[pix] - yp[pix - FW]; }
            else                  { g2x = 0.5f * (xp[pix + FW] - xp[pix - FW]);
                                    g2y = 0.5f * (yp[pix + FW] - yp[pix - FW]); }

            s += charb(g1x) + charb(g2x) + charb(g1y) + charb(g2y);
        }
        for (int off = 32; off > 0; off >>= 1) s += __shfl_down(s, off, 64);
        __shared__ float shs[4];
        int wave = threadIdx.x >> 6;
        if ((threadIdx.x & 63) == 0) shs[wave] = s;
        __syncthreads();
        if (threadIdx.x == 0)
            part_smooth[sb] = shs[0] + shs[1] + shs[2] + shs[3];
        return;
    }

    // ---------- loss block: (bc, 32-row part p) ----------
    __shared__ float slds[SROWS * FW];     // resized src part-plane + halo
    int blk = blockIdx.x - SMOOTH_BLOCKS;  // 0..1919
    int bc = blk >> 2;
    int p  = blk & 3;
    int b = bc / NC;
    int c = bc % NC;
    int f = c / 3;
    const float* ref_img  = images + (size_t)(b * ICH + c) * (IH * IW);
    const float* src_img  = images + (size_t)(b * ICH + 3 + c) * (IH * IW);
    const float* fx_plane = flows + (size_t)(b * 2 * NF + 2 * f) * PL;
    const float* fy_plane = fx_plane + PL;

    int lo = p * ROWS_PP - HALO;                    if (lo < 0) lo = 0;
    int hi = p * ROWS_PP + ROWS_PP - 1 + HALO + 1;  if (hi > FH - 1) hi = FH - 1;
    int nstage = (hi - lo + 1) * FW;

    // stage: resize src rows [lo,hi] into LDS (iterations independent -> ILP)
    #pragma unroll 2
    for (int i = threadIdx.x; i < nstage; i += 256) {
        int y = lo + (i >> 7);
        int x = i & (FW - 1);
        slds[i] = resized_at(src_img, y, x);
    }
    __syncthreads();

    // per-thread w-pair is loop-invariant: hoist all x-side resize weights
    const float sR = (float)(255.0 / 127.0);
    int w0 = (2 * threadIdx.x) & (FW - 1);          // pixels w0, w0+1
    float fx0 = (float)w0 * sR;
    float fx1 = (float)(w0 + 1) * sR;
    int x00 = (int)fx0; if (x00 > IW - 2) x00 = IW - 2;
    int x01 = (int)fx1; if (x01 > IW - 2) x01 = IW - 2;
    float wxr0 = fx0 - (float)x00;
    float wxr1 = fx1 - (float)x01;

    float s_ref = 0.f, s_w = 0.f, s_r2 = 0.f, s_w2 = 0.f, s_rw = 0.f, s_pix = 0.f;
    int base2 = p * (ROWS_PP * FW / 2);              // float2 pixel-pair index base
    for (int i = threadIdx.x; i < ROWS_PP * FW / 2; i += 256) {   // 8 iterations
        int p2 = base2 + i;
        int px = 2 * p2;
        int h = px >> 7;
        // --- ref resize, both pixels: 4 float2 loads (8B-aligned by construction, r8)
        float fyR = (float)h * sR;
        int yr0 = (int)fyR; if (yr0 > IH - 2) yr0 = IH - 2;
        float wyr = fyR - (float)yr0;
        const float* rp0 = ref_img + yr0 * IW;
        const float* rp1 = rp0 + IW;
        float2 a0 = *(const float2*)(rp0 + x00);   // a00, a01
        float2 a1 = *(const float2*)(rp1 + x00);   // a10, a11
        float2 b0 = *(const float2*)(rp0 + x01);   // b00, b01
        float2 b1 = *(const float2*)(rp1 + x01);   // b10, b11
        float2 fl_x = ((const float2*)fx_plane)[p2];
        float2 fl_y = ((const float2*)fy_plane)[p2];

        float ar0 = a0.x * (1.f - wyr) + a1.x * wyr;
        float ar1 = a0.y * (1.f - wyr) + a1.y * wyr;
        float ref0 = ar0 * (1.f - wxr0) + ar1 * wxr0;
        float br0 = b0.x * (1.f - wyr) + b1.x * wyr;
        float br1 = b0.y * (1.f - wyr) + b1.y * wyr;
        float ref1 = br0 * (1.f - wxr1) + br1 * wxr1;

        // --- warp sample from LDS, both pixels
        float wv[2];
        #pragma unroll
        for (int q = 0; q < 2; q++) {
            float gx = (float)(w0 + q) + (q ? fl_x.y : fl_x.x);
            float gy = (float)h + (q ? fl_y.y : fl_y.x);
            float x0f = floorf(gx), y0f = floorf(gy);
            float wx = gx - x0f, wy = gy - y0f;
            int x0 = (int)x0f; x0 = min(max(x0, 0), FW - 1);
            int y0 = (int)y0f; y0 = min(max(y0, 0), FH - 1);
            int x1 = min(x0 + 1, FW - 1);
            int y1 = min(y0 + 1, FH - 1);
            float v00, v01, v10, v11;
            if (y0 >= lo && y1 <= hi) {     // true unless |flow| > ~3-4 sigma
                const float* r0 = slds + ((y0 - lo) << 7);
                const float* r1 = slds + ((y1 - lo) << 7);
                v00 = r0[x0]; v01 = r0[x1];
                v10 = r1[x0]; v11 = r1[x1];
            } else {                         // exact recompute from global (rare)
                v00 = resized_at(src_img, y0, x0);
                v01 = resized_at(src_img, y0, x1);
                v10 = resized_at(src_img, y1, x0);
                v11 = resized_at(src_img, y1, x1);
            }
            float top = v00 * (1.f - wx) + v01 * wx;
            float bot = v10 * (1.f - wx) + v11 * wx;
            wv[q] = top * (1.f - wy) + bot * wy;
        }

        s_ref += ref0 + ref1;
        s_w   += wv[0] + wv[1];
        s_r2  += ref0 * ref0 + ref1 * ref1;
        s_w2  += wv[0] * wv[0] + wv[1] * wv[1];
        s_rw  += ref0 * wv[0] + ref1 * wv[1];
        s_pix += charb(ref0 - wv[0]) + charb(ref1 - wv[1]);
    }
    for (int off = 32; off > 0; off >>= 1) {
        s_ref += __shfl_down(s_ref, off, 64);
        s_w   += __shfl_down(s_w, off, 64);
        s_r2  += __shfl_down(s_r2, off, 64);
        s_w2  += __shfl_down(s_w2, off, 64);
        s_rw  += __shfl_down(s_rw, off, 64);
        s_pix += __shfl_down(s_pix, off, 64);
    }
    __shared__ float sh[4][6];
    int wave = threadIdx.x >> 6;
    if ((threadIdx.x & 63) == 0) {
        sh[wave][0] = s_ref; sh[wave][1] = s_w; sh[wave][2] = s_r2;
        sh[wave][3] = s_w2;  sh[wave][4] = s_rw; sh[wave][5] = s_pix;
    }
    __syncthreads();
    if (threadIdx.x < 6) {
        int k = threadIdx.x;
        part_loss[blk * PART_STRIDE + k] = sh[0][k] + sh[1][k] + sh[2][k] + sh[3][k];
    }
}

// ============ finalize: SSIM per (b,c) + combine to scalar ============
__global__ void __launch_bounds__(512) finalize2(const float* __restrict__ ws,
                                                 float* __restrict__ out)
{
    const float* part_loss   = ws;
    const float* part_smooth = ws + LOSS_BLOCKS * PART_STRIDE;
    int tid = threadIdx.x;
    float ssim = 0.f, pix = 0.f, smo = 0.f;
    if (tid < NB * NC) {
        float t0 = 0, t1 = 0, t2 = 0, t3 = 0, t4 = 0;
        for (int q = 0; q < SPLIT; q++) {
            const float* a = part_loss + (SPLIT * tid + q) * PART_STRIDE;
            t0 += a[0]; t1 += a[1]; t2 += a[2]; t3 += a[3]; t4 += a[4];
            pix += a[5];
        }
        const float N = (float)PL;
        float mu1 = t0 / N, mu2 = t1 / N;
        float var1 = (t2 - t0 * mu1) / (N - 1.f);
        float var2 = (t3 - t1 * mu2) / (N - 1.f);
        float s12 = t4 / N - mu1 * mu2;
        float num = (2.f * mu1 * mu2 + 1e-4f) * (2.f * s12 + 1e-3f);
        float den = (mu1 * mu1 + mu2 * mu2 + 1e-4f) * (var1 + var2 + 1e-3f);
        ssim = num / den;
    }
    if (tid < SMOOTH_BLOCKS) smo = part_smooth[tid];
    __shared__ float sa[512], sb[512], sc[512];
    sa[tid] = ssim; sb[tid] = pix; sc[tid] = smo;
    __syncthreads();
    for (int off = 256; off > 0; off >>= 1) {
        if (tid < off) {
            sa[tid] += sa[tid + off];
            sb[tid] += sb[tid + off];
            sc[tid] += sc[tid + off];
        }
        __syncthreads();
    }
    if (tid == 0) {
        out[0] = sb[0] / (float)(NB * NC * PL)
               + 0.01f * (sc[0] / (float)(NB * NF * PL))
               + sa[0] / (float)(NB * NC);
    }
}

extern "C" void kernel_launch(void* const* d_in, const int* in_sizes, int n_in,
                              void* d_out, int out_size, void* d_ws, size_t ws_size,
                              hipStream_t stream) {
    const float* images = (const float*)d_in[0];
    const float* flows  = (const float*)d_in[1];
    float* ws = (float*)d_ws;   // ~62 KB of plain-stored partials
    mega<<<SMOOTH_BLOCKS + LOSS_BLOCKS, 256, 0, stream>>>(images, flows, ws);
    finalize2<<<1, 512, 0, stream>>>(ws, (float*)d_out);
}